// Round 25
// baseline (183.403 us; speedup 1.0000x reference)
//
#include <hip/hip_runtime.h>

#define BATCH 4096
#define NF 128
#define NW 128
#define NO 32

// d_ws (u16 elems): wh fp16 [l,f][v][k-perm] | wo fp16 [f][o][k-perm] | xT fp32 [f][m]
#define WH_ELEMS (2 * 128 * 128 * 128)
#define WO_ELEMS (128 * 128 * 32)

typedef _Float16 f16x8 __attribute__((ext_vector_type(8)));
typedef float f32x16 __attribute__((ext_vector_type(16)));
typedef unsigned u32x4 __attribute__((ext_vector_type(4)));

static __device__ __forceinline__ unsigned short f2h(float f) {
    return __builtin_bit_cast(unsigned short, (_Float16)f);  // RNE (prep only)
}
static __device__ __forceinline__ unsigned pkrtz(float a, float b) {
    return __builtin_bit_cast(unsigned, __builtin_amdgcn_cvt_pkrtz(a, b));
}
// k-pair permutation: slot-pair sp (0..7 per 16k-block) reads k-pair with
// bits 1,2 swapped: pi2 = [0,1,4,5,2,3,6,7]. Derived from the verified C
// layout (reg r -> row (r&3)+8(r>>2)+4khalf): khalf 0 holds v{0-3,8-11},
// khalf 1 holds {4-7,12-15} per 16-block.
static __device__ __forceinline__ int ksrc_pair(int kp) {
    int lp = kp & 7;
    int sp = (lp & 1) | ((lp & 2) << 1) | ((lp & 4) >> 1);
    return (kp & ~7) | sp;
}

// Transpose+fp16+k-permute weights (0..383), zero out (384..399), transpose x (400..431).
__global__ __launch_bounds__(256) void prep_weights5(
    const float* __restrict__ Wh, const float* __restrict__ Wo,
    const float* __restrict__ x, unsigned short* __restrict__ ws,
    float* __restrict__ out) {
    __shared__ __align__(16) unsigned char sm_raw[128 * 129 * 4];
    unsigned short* t_sm = (unsigned short*)sm_raw;
    float* ts = (float*)sm_raw;
    unsigned short* wh = ws;
    unsigned short* wo = ws + WH_ELEMS;
    float* xT = (float*)(ws + WH_ELEMS + WO_ELEMS);
    const int b = blockIdx.x;
    const int tid = threadIdx.x;
    if (b < 256) {
        const float* src = Wh + (size_t)b * 16384;  // [k][v]
        for (int i = tid; i < 16384; i += 256) {
            int k = i >> 7, v = i & 127;
            t_sm[v * 138 + k] = f2h(src[i]);  // coalesced read
        }
        __syncthreads();
        unsigned short* dst = wh + (size_t)b * 16384;  // [v][k-perm]
        for (int i = tid; i < 8192; i += 256) {
            int v = i >> 6, kp = i & 63;
            int sk = ksrc_pair(kp);
            unsigned lo = t_sm[v * 138 + 2 * sk];
            unsigned hi = t_sm[v * 138 + 2 * sk + 1];
            *(unsigned*)&dst[v * 128 + 2 * kp] = lo | (hi << 16);  // coalesced write
        }
    } else if (b < 384) {
        const int f = b - 256;
        const float* src = Wo + (size_t)f * 4096;  // [k][o]
        for (int i = tid; i < 4096; i += 256) {
            int k = i >> 5, o = i & 31;
            t_sm[o * 138 + k] = f2h(src[i]);
        }
        __syncthreads();
        unsigned short* dst = wo + (size_t)f * 4096;  // [o][k-perm]
        for (int i = tid; i < 2048; i += 256) {
            int o = i >> 6, kp = i & 63;
            int sk = ksrc_pair(kp);
            unsigned lo = t_sm[o * 138 + 2 * sk];
            unsigned hi = t_sm[o * 138 + 2 * sk + 1];
            *(unsigned*)&dst[o * 128 + 2 * kp] = lo | (hi << 16);
        }
    } else if (b < 400) {
        const int zb = b - 384;
        float4 z = (float4){0.f, 0.f, 0.f, 0.f};
        for (int i = zb * 256 + tid; i < BATCH * NO / 4; i += 16 * 256)
            *(float4*)&out[i * 4] = z;
    } else {
        const int mb = (b - 400) * 128;
        for (int i = tid; i < 128 * 128; i += 256) {
            int r = i >> 7, f = i & 127;
            ts[f * 129 + r] = x[(size_t)(mb + r) * NF + f];
        }
        __syncthreads();
        for (int i = tid; i < 128 * 128; i += 256) {
            int f = i >> 7, r = i & 127;
            xT[(size_t)f * BATCH + mb + r] = ts[f * 129 + r];
        }
    }
}

// One hidden layer entirely in registers: C[v][m] = Wt_perm . h^T per 32v
// tile. Because weights are k-permuted by pi, the accumulator registers ARE
// the next layer's B-fragment in natural order: no cross-lane ops at all.
static __device__ __forceinline__ void hidden_layer(
    unsigned (&hin)[8][4], unsigned (&hout)[8][4],
    const unsigned short* __restrict__ wp, const float* __restrict__ bhl,
    int l31, int khalf) {
#pragma unroll
    for (int vt = 0; vt < 4; ++vt) {
        f32x16 acc;  // C tile: col=l31, row v = 32vt + (r&3)+8(r>>2)+4khalf
#pragma unroll
        for (int q = 0; q < 4; ++q) {
            float4 bb4 = *(const float4*)&bhl[32 * vt + 8 * q + 4 * khalf];
            acc[4 * q + 0] = bb4.x; acc[4 * q + 1] = bb4.y;
            acc[4 * q + 2] = bb4.z; acc[4 * q + 3] = bb4.w;
        }
        __builtin_amdgcn_s_setprio(1);
#pragma unroll
        for (int kh = 0; kh < 2; ++kh) {
            f16x8 A[4];
#pragma unroll
            for (int k2 = 0; k2 < 4; ++k2)
                A[k2] = *(const f16x8*)&wp[(32 * vt + l31) * 128 + (kh * 4 + k2) * 16 + khalf * 8];
#pragma unroll
            for (int k2 = 0; k2 < 4; ++k2) {
                int ks = kh * 4 + k2;
                u32x4 bu = (u32x4){hin[ks][0], hin[ks][1], hin[ks][2], hin[ks][3]};
                acc = __builtin_amdgcn_mfma_f32_32x32x16_f16(
                    A[k2], __builtin_bit_cast(f16x8, bu), acc, 0, 0, 0);
            }
        }
        __builtin_amdgcn_s_setprio(0);
        // ReLU + pack: accumulator order == B-fragment order (pi-permuted weights)
#pragma unroll
        for (int qp = 0; qp < 2; ++qp) {
            hout[2 * vt + qp][0] = pkrtz(fmaxf(acc[8 * qp + 0], 0.f), fmaxf(acc[8 * qp + 1], 0.f));
            hout[2 * vt + qp][1] = pkrtz(fmaxf(acc[8 * qp + 2], 0.f), fmaxf(acc[8 * qp + 3], 0.f));
            hout[2 * vt + qp][2] = pkrtz(fmaxf(acc[8 * qp + 4], 0.f), fmaxf(acc[8 * qp + 5], 0.f));
            hout[2 * vt + qp][3] = pkrtz(fmaxf(acc[8 * qp + 6], 0.f), fmaxf(acc[8 * qp + 7], 0.f));
        }
    }
}

// Wave-autonomous fused chain: 32 batch rows per wave, h in registers,
// NO LDS, NO barriers, NO cross-lane ops. Weights from L2 (XCD-swizzled).
__global__ __launch_bounds__(256, 4) void ngam_fused(
    const float* __restrict__ W1, const float* __restrict__ b1,
    const float* __restrict__ bh, const float* __restrict__ bo,
    const unsigned short* __restrict__ ws, float* __restrict__ out) {
    const unsigned short* wh = ws;
    const unsigned short* wo = ws + WH_ELEMS;
    const float* xT = (const float*)(ws + WH_ELEMS + WO_ELEMS);

    const int bid   = blockIdx.x;                    // grid = 4096 (r23/r24 bug: was 2048)
    const int lb    = (bid & 7) * 512 + (bid >> 3);  // XCD-chunked bijection
    const int f     = lb >> 5;
    const int m0w   = (lb & 31) * 128 + (threadIdx.x >> 6) * 32;
    const int lane  = threadIdx.x & 63;
    const int l31   = lane & 31;   // m (B col / C col / A row of h)
    const int khalf = lane >> 5;   // k-half

    unsigned hA[8][4], hB[8][4];  // packed h in B-fragment order

    // ---- layer 0: h = relu(x*W1+b1), fp32 exact, computed in pi-order ----
    // lane khalf holds w = 16ks + 4khalf + {0..3} and 16ks + 8 + 4khalf + {0..3}
    {
        float xv = xT[(size_t)f * BATCH + m0w + l31];
        const float* w1r = &W1[f * NW];
        const float* b1r = &b1[f * NW];
#pragma unroll
        for (int ks = 0; ks < 8; ++ks) {
            float4 wa = *(const float4*)&w1r[ks * 16 + 4 * khalf];
            float4 ba = *(const float4*)&b1r[ks * 16 + 4 * khalf];
            float4 wb = *(const float4*)&w1r[ks * 16 + 8 + 4 * khalf];
            float4 bb = *(const float4*)&b1r[ks * 16 + 8 + 4 * khalf];
            hA[ks][0] = pkrtz(fmaxf(xv * wa.x + ba.x, 0.f), fmaxf(xv * wa.y + ba.y, 0.f));
            hA[ks][1] = pkrtz(fmaxf(xv * wa.z + ba.z, 0.f), fmaxf(xv * wa.w + ba.w, 0.f));
            hA[ks][2] = pkrtz(fmaxf(xv * wb.x + bb.x, 0.f), fmaxf(xv * wb.y + bb.y, 0.f));
            hA[ks][3] = pkrtz(fmaxf(xv * wb.z + bb.z, 0.f), fmaxf(xv * wb.w + bb.w, 0.f));
        }
    }

    // ---- two hidden layers, ping-pong h register banks ----
    hidden_layer(hA, hB, wh + (size_t)(0 * NF + f) * 16384, bh + (size_t)(0 * NF + f) * NW, l31, khalf);
    hidden_layer(hB, hA, wh + (size_t)(1 * NF + f) * 16384, bh + (size_t)(1 * NF + f) * NW, l31, khalf);

    // ---- output layer: C[m][o] = h . Wo_perm (h-regs ARE the A-fragment) ----
    {
        const unsigned short* wop = wo + (size_t)f * 4096;
        float bv = bo[f * NO + l31];
        f32x16 acc2;
#pragma unroll
        for (int i = 0; i < 16; ++i) acc2[i] = bv;
        __builtin_amdgcn_s_setprio(1);
#pragma unroll
        for (int kh = 0; kh < 2; ++kh) {
            f16x8 Bo[4];
#pragma unroll
            for (int k2 = 0; k2 < 4; ++k2)
                Bo[k2] = *(const f16x8*)&wop[l31 * 128 + (kh * 4 + k2) * 16 + khalf * 8];
#pragma unroll
            for (int k2 = 0; k2 < 4; ++k2) {
                int ks = kh * 4 + k2;
                u32x4 au = (u32x4){hA[ks][0], hA[ks][1], hA[ks][2], hA[ks][3]};
                acc2 = __builtin_amdgcn_mfma_f32_32x32x16_f16(
                    __builtin_bit_cast(f16x8, au), Bo[k2], acc2, 0, 0, 0);
            }
        }
        __builtin_amdgcn_s_setprio(0);
        // merged atomics: 32 lanes of a khalf hit one 128B line of out
#pragma unroll
        for (int r = 0; r < 16; ++r) {
            int row = m0w + (r & 3) + 8 * (r >> 2) + 4 * khalf;
            atomicAdd(&out[(size_t)row * NO + l31], acc2[r]);
        }
    }
}

extern "C" void kernel_launch(void* const* d_in, const int* in_sizes, int n_in,
                              void* d_out, int out_size, void* d_ws, size_t ws_size,
                              hipStream_t stream) {
    const float* x  = (const float*)d_in[0];
    const float* W1 = (const float*)d_in[1];
    const float* b1 = (const float*)d_in[2];
    const float* Wh = (const float*)d_in[3];
    const float* bh = (const float*)d_in[4];
    const float* Wo = (const float*)d_in[5];
    const float* bo = (const float*)d_in[6];
    float* out = (float*)d_out;
    unsigned short* ws = (unsigned short*)d_ws;

    prep_weights5<<<432, 256, 0, stream>>>(Wh, Wo, x, ws, out);
    // 4096 blocks: 128 features x 32 row-tiles (4 waves x 32 rows each)
    ngam_fused<<<4096, 256, 0, stream>>>(W1, b1, bh, bo, ws, out);
}

// Round 26
// 99.498 us; speedup vs baseline: 1.8433x; 1.8433x over previous
//
#include <hip/hip_runtime.h>

#define BATCH 4096
#define NF 128
#define NW 128
#define NO 32
#define MT 128    // batch rows per block
#define LDH 136   // h stride in u16 (272B rows: 16B-aligned)

// d_ws (u16 elems): wh fp16 [l,f][v][k] | wo fp16 [f][o][k] | xT fp32 [f][m]
#define WH_ELEMS (2 * 128 * 128 * 128)
#define WO_ELEMS (128 * 128 * 32)

typedef _Float16 f16x8 __attribute__((ext_vector_type(8)));
typedef float f32x16 __attribute__((ext_vector_type(16)));

static __device__ __forceinline__ unsigned short f2h(float f) {
    return __builtin_bit_cast(unsigned short, (_Float16)f);  // RNE (prep only)
}
// 2x v_cvt_pkrtz_f16_f32: 2 VALU per 4 values
static __device__ __forceinline__ unsigned long long pack4rtz(float a, float b, float c, float d) {
    unsigned lo = __builtin_bit_cast(unsigned, __builtin_amdgcn_cvt_pkrtz(a, b));
    unsigned hi = __builtin_bit_cast(unsigned, __builtin_amdgcn_cvt_pkrtz(c, d));
    return (unsigned long long)lo | ((unsigned long long)hi << 32);
}

// Transpose+fp16 weights (0..383), zero out (384..399), transpose x (400..431).
__global__ __launch_bounds__(256) void prep_weights4(
    const float* __restrict__ Wh, const float* __restrict__ Wo,
    const float* __restrict__ x, unsigned short* __restrict__ ws,
    float* __restrict__ out) {
    __shared__ __align__(16) unsigned char sm_raw[128 * 129 * 4];
    unsigned short* t_sm = (unsigned short*)sm_raw;
    float* ts = (float*)sm_raw;
    unsigned short* wh = ws;
    unsigned short* wo = ws + WH_ELEMS;
    float* xT = (float*)(ws + WH_ELEMS + WO_ELEMS);
    const int b = blockIdx.x;
    const int tid = threadIdx.x;
    if (b < 256) {
        const float* src = Wh + (size_t)b * 16384;  // [k][v]
        for (int i = tid; i < 16384; i += 256) {
            int k = i >> 7, v = i & 127;
            t_sm[v * 138 + k] = f2h(src[i]);  // coalesced read
        }
        __syncthreads();
        unsigned short* dst = wh + (size_t)b * 16384;  // [v][k]
        for (int i = tid; i < 8192; i += 256) {
            int v = i >> 6, kp = i & 63;
            unsigned lo = t_sm[v * 138 + 2 * kp];
            unsigned hi = t_sm[v * 138 + 2 * kp + 1];
            *(unsigned*)&dst[v * 128 + 2 * kp] = lo | (hi << 16);  // coalesced write
        }
    } else if (b < 384) {
        const int f = b - 256;
        const float* src = Wo + (size_t)f * 4096;  // [k][o]
        for (int i = tid; i < 4096; i += 256) {
            int k = i >> 5, o = i & 31;
            t_sm[o * 138 + k] = f2h(src[i]);
        }
        __syncthreads();
        unsigned short* dst = wo + (size_t)f * 4096;  // [o][k]
        for (int i = tid; i < 2048; i += 256) {
            int o = i >> 6, kp = i & 63;
            unsigned lo = t_sm[o * 138 + 2 * kp];
            unsigned hi = t_sm[o * 138 + 2 * kp + 1];
            *(unsigned*)&dst[o * 128 + 2 * kp] = lo | (hi << 16);
        }
    } else if (b < 400) {
        const int zb = b - 384;
        float4 z = (float4){0.f, 0.f, 0.f, 0.f};
        for (int i = zb * 256 + tid; i < BATCH * NO / 4; i += 16 * 256)
            *(float4*)&out[i * 4] = z;
    } else {
        // transpose x[4096][128] -> xT[128][4096], 128-row slab per block
        const int mb = (b - 400) * 128;
        for (int i = tid; i < 128 * 128; i += 256) {
            int r = i >> 7, f = i & 127;
            ts[f * 129 + r] = x[(size_t)(mb + r) * NF + f];
        }
        __syncthreads();
        for (int i = tid; i < 128 * 128; i += 256) {
            int f = i >> 7, r = i & 127;
            xT[(size_t)f * BATCH + mb + r] = ts[f * 129 + r];
        }
    }
}

// Champion structure (r22): 32x32x16 MFMA, swapped hidden (C[v][m]=Wt.h^T),
// unswapped output (merged atomics), pack4rtz, coalesced L0 via xT,
// XCD-chunked block swizzle (weights L2-resident per XCD), s_setprio around
// MFMA clusters. Register ledger: 60 arch + 64 AGPR = 124/128, 4 blocks/CU.
// r23-r25 lesson: wave-autonomous (no-LDS) alternative needs 4x weight regs
// per wave -> L2-latency-exposed at 178us; LDS-shared-h amortizes better.
__global__ __launch_bounds__(256, 4) void ngam_fused(
    const float* __restrict__ W1, const float* __restrict__ b1,
    const float* __restrict__ bh, const float* __restrict__ bo,
    const unsigned short* __restrict__ ws, float* __restrict__ out) {
    __shared__ __align__(16) unsigned short h_sm[MT * LDH];
    const unsigned short* wh = ws;
    const unsigned short* wo = ws + WH_ELEMS;
    const float* xT = (const float*)(ws + WH_ELEMS + WO_ELEMS);

    // XCD-chunked bijective swizzle (4096 = 8 XCDs x 512): XCD k owns
    // logical blocks [k*512, (k+1)*512) = features [k*16, (k+1)*16).
    const int bid   = blockIdx.x;
    const int lb    = (bid & 7) * 512 + (bid >> 3);
    const int f     = lb >> 5;
    const int m0    = (lb & 31) * MT;
    const int tid   = threadIdx.x;
    const int wave  = tid >> 6;
    const int lane  = tid & 63;
    const int l31   = lane & 31;              // A row (v) / B col (m/o) / C col
    const int khalf = lane >> 5;              // k-half: kbase = 8*khalf

    // ---- layer 0: h = relu(x*W1+b1), fp32 exact -> fp16 LDS [m][w] ----
    {
        int m = tid >> 1, c = tid & 1;
        float xv = xT[(size_t)f * BATCH + m0 + m];  // coalesced
        const float* w1r = &W1[f * NW];
        const float* b1r = &b1[f * NW];
        for (int jh = 0; jh < 2; ++jh) {
#pragma unroll
            for (int j = 0; j < 8; ++j) {
                int wq = c * 64 + (jh * 8 + j) * 4;
                float4 w1 = *(const float4*)&w1r[wq];
                float4 bb = *(const float4*)&b1r[wq];
                float v0 = fmaxf(xv * w1.x + bb.x, 0.0f);
                float v1 = fmaxf(xv * w1.y + bb.y, 0.0f);
                float v2 = fmaxf(xv * w1.z + bb.z, 0.0f);
                float v3 = fmaxf(xv * w1.w + bb.w, 0.0f);
                *(unsigned long long*)&h_sm[m * LDH + wq] = pack4rtz(v0, v1, v2, v3);
            }
        }
    }
    __syncthreads();

    // ---- two hidden layers (swapped: C[v][m] = Wt . h^T, 32x32 tiles) ----
#pragma unroll
    for (int l = 0; l < 2; ++l) {
        const unsigned short* wp = wh + (size_t)(l * NF + f) * 16384;
        const float* bhl = bh + (size_t)(l * NF + f) * NW;

        f16x8 A[8];  // wave's 32v x 128k A panel: 8 b128 (32 regs)
#pragma unroll
        for (int ks = 0; ks < 8; ++ks)
            A[ks] = *(const f16x8*)&wp[(wave * 32 + l31) * 128 + ks * 16 + khalf * 8];

        f32x16 binit;
#pragma unroll
        for (int q = 0; q < 4; ++q) {
            float4 bb4 = *(const float4*)&bhl[wave * 32 + 8 * q + 4 * khalf];
            binit[4 * q + 0] = bb4.x; binit[4 * q + 1] = bb4.y;
            binit[4 * q + 2] = bb4.z; binit[4 * q + 3] = bb4.w;
        }
        f32x16 acc[4];  // [mt] = 64 AGPRs
#pragma unroll
        for (int mt = 0; mt < 4; ++mt) acc[mt] = binit;

        __builtin_amdgcn_s_setprio(1);
#pragma unroll
        for (int mt = 0; mt < 4; ++mt) {
#pragma unroll
            for (int ks = 0; ks < 8; ++ks) {
                f16x8 bfr = *(const f16x8*)&h_sm[(mt * 32 + l31) * LDH + ks * 16 + khalf * 8];
                acc[mt] = __builtin_amdgcn_mfma_f32_32x32x16_f16(A[ks], bfr, acc[mt], 0, 0, 0);
            }
        }
        __builtin_amdgcn_s_setprio(0);
        __syncthreads();  // all waves done reading h
        // ReLU + b64 packed writeback: m = mt*32+l31, v = wave*32+8q+4*khalf+[0..3]
#pragma unroll
        for (int mt = 0; mt < 4; ++mt)
#pragma unroll
            for (int q = 0; q < 4; ++q)
                *(unsigned long long*)&h_sm[(mt * 32 + l31) * LDH + wave * 32 + 8 * q + 4 * khalf] =
                    pack4rtz(fmaxf(acc[mt][4 * q + 0], 0.f), fmaxf(acc[mt][4 * q + 1], 0.f),
                             fmaxf(acc[mt][4 * q + 2], 0.f), fmaxf(acc[mt][4 * q + 3], 0.f));
        __syncthreads();  // writeback visible
    }

    // ---- output layer (UNSWAPPED: C[m][o] = h . Wo, one 32x32 tile) ----
    {
        const unsigned short* wop = wo + (size_t)f * 4096;
        const float* bof = bo + (size_t)f * NO;
        f16x8 Bo[8];
#pragma unroll
        for (int ks = 0; ks < 8; ++ks)
            Bo[ks] = *(const f16x8*)&wop[l31 * 128 + ks * 16 + khalf * 8];
        float bv = bof[l31];
        f32x16 acc2;
#pragma unroll
        for (int i = 0; i < 16; ++i) acc2[i] = bv;
        __builtin_amdgcn_s_setprio(1);
#pragma unroll
        for (int ks = 0; ks < 8; ++ks) {
            f16x8 a = *(const f16x8*)&h_sm[(wave * 32 + l31) * LDH + ks * 16 + khalf * 8];
            acc2 = __builtin_amdgcn_mfma_f32_32x32x16_f16(a, Bo[ks], acc2, 0, 0, 0);
        }
        __builtin_amdgcn_s_setprio(0);
        // atomics: reg r -> row = m0+wave*32+(r&3)+8(r>>2)+4*khalf, col = l31
        // (32 lanes hit one full 128B line of out -> fully merged)
#pragma unroll
        for (int r = 0; r < 16; ++r) {
            int row = m0 + wave * 32 + (r & 3) + 8 * (r >> 2) + 4 * khalf;
            atomicAdd(&out[(size_t)row * NO + l31], acc2[r]);
        }
    }
}

extern "C" void kernel_launch(void* const* d_in, const int* in_sizes, int n_in,
                              void* d_out, int out_size, void* d_ws, size_t ws_size,
                              hipStream_t stream) {
    const float* x  = (const float*)d_in[0];
    const float* W1 = (const float*)d_in[1];
    const float* b1 = (const float*)d_in[2];
    const float* Wh = (const float*)d_in[3];
    const float* bh = (const float*)d_in[4];
    const float* Wo = (const float*)d_in[5];
    const float* bo = (const float*)d_in[6];
    float* out = (float*)d_out;
    unsigned short* ws = (unsigned short*)d_ws;

    prep_weights4<<<432, 256, 0, stream>>>(Wh, Wo, x, ws, out);
    ngam_fused<<<NF * (BATCH / MT), 256, 0, stream>>>(W1, b1, bh, bo, ws, out);
}

// Round 27
// 97.827 us; speedup vs baseline: 1.8748x; 1.0171x over previous
//
#include <hip/hip_runtime.h>

#define BATCH 4096
#define NF 128
#define NW 128
#define NO 32
#define MT 128    // batch rows per block
#define LDH 136   // h stride in u16 (272B rows: 16B-aligned)

// d_ws (u16 elems): wh fp16 [l,f][v][k] | wo fp16 [f][o][k] | xT fp32 [f][m]
#define WH_ELEMS (2 * 128 * 128 * 128)
#define WO_ELEMS (128 * 128 * 32)

typedef _Float16 f16x8 __attribute__((ext_vector_type(8)));
typedef float f32x16 __attribute__((ext_vector_type(16)));

static __device__ __forceinline__ unsigned short f2h(float f) {
    return __builtin_bit_cast(unsigned short, (_Float16)f);  // RNE (prep only)
}
// 2x v_cvt_pkrtz_f16_f32: 2 VALU per 4 values
static __device__ __forceinline__ unsigned long long pack4rtz(float a, float b, float c, float d) {
    unsigned lo = __builtin_bit_cast(unsigned, __builtin_amdgcn_cvt_pkrtz(a, b));
    unsigned hi = __builtin_bit_cast(unsigned, __builtin_amdgcn_cvt_pkrtz(c, d));
    return (unsigned long long)lo | ((unsigned long long)hi << 32);
}

// Transpose+fp16 weights (0..383), zero out (384..399), transpose x (400..431).
__global__ __launch_bounds__(256) void prep_weights4(
    const float* __restrict__ Wh, const float* __restrict__ Wo,
    const float* __restrict__ x, unsigned short* __restrict__ ws,
    float* __restrict__ out) {
    __shared__ __align__(16) unsigned char sm_raw[128 * 129 * 4];
    unsigned short* t_sm = (unsigned short*)sm_raw;
    float* ts = (float*)sm_raw;
    unsigned short* wh = ws;
    unsigned short* wo = ws + WH_ELEMS;
    float* xT = (float*)(ws + WH_ELEMS + WO_ELEMS);
    const int b = blockIdx.x;
    const int tid = threadIdx.x;
    if (b < 256) {
        const float* src = Wh + (size_t)b * 16384;  // [k][v]
        for (int i = tid; i < 16384; i += 256) {
            int k = i >> 7, v = i & 127;
            t_sm[v * 138 + k] = f2h(src[i]);  // coalesced read
        }
        __syncthreads();
        unsigned short* dst = wh + (size_t)b * 16384;  // [v][k]
        for (int i = tid; i < 8192; i += 256) {
            int v = i >> 6, kp = i & 63;
            unsigned lo = t_sm[v * 138 + 2 * kp];
            unsigned hi = t_sm[v * 138 + 2 * kp + 1];
            *(unsigned*)&dst[v * 128 + 2 * kp] = lo | (hi << 16);  // coalesced write
        }
    } else if (b < 384) {
        const int f = b - 256;
        const float* src = Wo + (size_t)f * 4096;  // [k][o]
        for (int i = tid; i < 4096; i += 256) {
            int k = i >> 5, o = i & 31;
            t_sm[o * 138 + k] = f2h(src[i]);
        }
        __syncthreads();
        unsigned short* dst = wo + (size_t)f * 4096;  // [o][k]
        for (int i = tid; i < 2048; i += 256) {
            int o = i >> 6, kp = i & 63;
            unsigned lo = t_sm[o * 138 + 2 * kp];
            unsigned hi = t_sm[o * 138 + 2 * kp + 1];
            *(unsigned*)&dst[o * 128 + 2 * kp] = lo | (hi << 16);
        }
    } else if (b < 400) {
        const int zb = b - 384;
        float4 z = (float4){0.f, 0.f, 0.f, 0.f};
        for (int i = zb * 256 + tid; i < BATCH * NO / 4; i += 16 * 256)
            *(float4*)&out[i * 4] = z;
    } else {
        // transpose x[4096][128] -> xT[128][4096], 128-row slab per block
        const int mb = (b - 400) * 128;
        for (int i = tid; i < 128 * 128; i += 256) {
            int r = i >> 7, f = i & 127;
            ts[f * 129 + r] = x[(size_t)(mb + r) * NF + f];
        }
        __syncthreads();
        for (int i = tid; i < 128 * 128; i += 256) {
            int f = i >> 7, r = i & 127;
            xT[(size_t)f * BATCH + mb + r] = ts[f * 129 + r];
        }
    }
}

// Champion (r22/r26) + cross-barrier weight prefetch: the 2-layer loop is
// manually unrolled and each next stage's weight panel (A2, then Bo) is
// loaded right AFTER the current MFMA cluster (its registers are dead) and
// BEFORE the writeback barriers -- the compiler's vmcnt(0)-drain-at-barrier
// completes them where the wave idles anyway, removing the ~300cy L2
// round-trip from the post-barrier serial path. Register-neutral: exactly
// one 32-reg panel live at a time beside the 64-AGPR acc (124/128).
__global__ __launch_bounds__(256, 4) void ngam_fused(
    const float* __restrict__ W1, const float* __restrict__ b1,
    const float* __restrict__ bh, const float* __restrict__ bo,
    const unsigned short* __restrict__ ws, float* __restrict__ out) {
    __shared__ __align__(16) unsigned short h_sm[MT * LDH];
    const unsigned short* wh = ws;
    const unsigned short* wo = ws + WH_ELEMS;
    const float* xT = (const float*)(ws + WH_ELEMS + WO_ELEMS);

    // XCD-chunked bijective swizzle (4096 = 8 XCDs x 512)
    const int bid   = blockIdx.x;
    const int lb    = (bid & 7) * 512 + (bid >> 3);
    const int f     = lb >> 5;
    const int m0    = (lb & 31) * MT;
    const int tid   = threadIdx.x;
    const int wave  = tid >> 6;
    const int lane  = tid & 63;
    const int l31   = lane & 31;              // A row (v) / B col (m/o) / C col
    const int khalf = lane >> 5;              // k-half: kbase = 8*khalf

    const unsigned short* wp0 = wh + (size_t)(0 * NF + f) * 16384;
    const unsigned short* wp1 = wh + (size_t)(1 * NF + f) * 16384;
    const unsigned short* wop = wo + (size_t)f * 4096;

    // ---- layer-0 A panel loads issue first (deepest latency to hide) ----
    f16x8 A[8];
#pragma unroll
    for (int ks = 0; ks < 8; ++ks)
        A[ks] = *(const f16x8*)&wp0[(wave * 32 + l31) * 128 + ks * 16 + khalf * 8];

    // ---- layer 0: h = relu(x*W1+b1), fp32 exact -> fp16 LDS [m][w] ----
    {
        int m = tid >> 1, c = tid & 1;
        float xv = xT[(size_t)f * BATCH + m0 + m];  // coalesced
        const float* w1r = &W1[f * NW];
        const float* b1r = &b1[f * NW];
        for (int jh = 0; jh < 2; ++jh) {
#pragma unroll
            for (int j = 0; j < 8; ++j) {
                int wq = c * 64 + (jh * 8 + j) * 4;
                float4 w1 = *(const float4*)&w1r[wq];
                float4 bb = *(const float4*)&b1r[wq];
                float v0 = fmaxf(xv * w1.x + bb.x, 0.0f);
                float v1 = fmaxf(xv * w1.y + bb.y, 0.0f);
                float v2 = fmaxf(xv * w1.z + bb.z, 0.0f);
                float v3 = fmaxf(xv * w1.w + bb.w, 0.0f);
                *(unsigned long long*)&h_sm[m * LDH + wq] = pack4rtz(v0, v1, v2, v3);
            }
        }
    }
    __syncthreads();

    // ================= hidden layer 1 =================
    {
        const float* bhl = bh + (size_t)(0 * NF + f) * NW;
        f32x16 binit;
#pragma unroll
        for (int q = 0; q < 4; ++q) {
            float4 bb4 = *(const float4*)&bhl[wave * 32 + 8 * q + 4 * khalf];
            binit[4 * q + 0] = bb4.x; binit[4 * q + 1] = bb4.y;
            binit[4 * q + 2] = bb4.z; binit[4 * q + 3] = bb4.w;
        }
        f32x16 acc[4];
#pragma unroll
        for (int mt = 0; mt < 4; ++mt) acc[mt] = binit;

        __builtin_amdgcn_s_setprio(1);
#pragma unroll
        for (int mt = 0; mt < 4; ++mt) {
#pragma unroll
            for (int ks = 0; ks < 8; ++ks) {
                f16x8 bfr = *(const f16x8*)&h_sm[(mt * 32 + l31) * LDH + ks * 16 + khalf * 8];
                acc[mt] = __builtin_amdgcn_mfma_f32_32x32x16_f16(A[ks], bfr, acc[mt], 0, 0, 0);
            }
        }
        __builtin_amdgcn_s_setprio(0);

        // PREFETCH layer-2 A panel (A regs dead) -- latency absorbs into
        // the barrier drain + writeback below.
#pragma unroll
        for (int ks = 0; ks < 8; ++ks)
            A[ks] = *(const f16x8*)&wp1[(wave * 32 + l31) * 128 + ks * 16 + khalf * 8];

        __syncthreads();  // all waves done reading h
#pragma unroll
        for (int mt = 0; mt < 4; ++mt)
#pragma unroll
            for (int q = 0; q < 4; ++q)
                *(unsigned long long*)&h_sm[(mt * 32 + l31) * LDH + wave * 32 + 8 * q + 4 * khalf] =
                    pack4rtz(fmaxf(acc[mt][4 * q + 0], 0.f), fmaxf(acc[mt][4 * q + 1], 0.f),
                             fmaxf(acc[mt][4 * q + 2], 0.f), fmaxf(acc[mt][4 * q + 3], 0.f));
        __syncthreads();  // writeback visible
    }

    // ================= hidden layer 2 =================
    {
        const float* bhl = bh + (size_t)(1 * NF + f) * NW;
        f32x16 binit;
#pragma unroll
        for (int q = 0; q < 4; ++q) {
            float4 bb4 = *(const float4*)&bhl[wave * 32 + 8 * q + 4 * khalf];
            binit[4 * q + 0] = bb4.x; binit[4 * q + 1] = bb4.y;
            binit[4 * q + 2] = bb4.z; binit[4 * q + 3] = bb4.w;
        }
        f32x16 acc[4];
#pragma unroll
        for (int mt = 0; mt < 4; ++mt) acc[mt] = binit;

        __builtin_amdgcn_s_setprio(1);
#pragma unroll
        for (int mt = 0; mt < 4; ++mt) {
#pragma unroll
            for (int ks = 0; ks < 8; ++ks) {
                f16x8 bfr = *(const f16x8*)&h_sm[(mt * 32 + l31) * LDH + ks * 16 + khalf * 8];
                acc[mt] = __builtin_amdgcn_mfma_f32_32x32x16_f16(A[ks], bfr, acc[mt], 0, 0, 0);
            }
        }
        __builtin_amdgcn_s_setprio(0);

        // PREFETCH output-layer Bo panel into the (dead) A registers.
#pragma unroll
        for (int ks = 0; ks < 8; ++ks)
            A[ks] = *(const f16x8*)&wop[l31 * 128 + ks * 16 + khalf * 8];

        __syncthreads();
#pragma unroll
        for (int mt = 0; mt < 4; ++mt)
#pragma unroll
            for (int q = 0; q < 4; ++q)
                *(unsigned long long*)&h_sm[(mt * 32 + l31) * LDH + wave * 32 + 8 * q + 4 * khalf] =
                    pack4rtz(fmaxf(acc[mt][4 * q + 0], 0.f), fmaxf(acc[mt][4 * q + 1], 0.f),
                             fmaxf(acc[mt][4 * q + 2], 0.f), fmaxf(acc[mt][4 * q + 3], 0.f));
        __syncthreads();
    }

    // ---- output layer (UNSWAPPED: C[m][o] = h . Wo; Bo already in A) ----
    {
        float bv = bo[f * NO + l31];
        f32x16 acc2;
#pragma unroll
        for (int i = 0; i < 16; ++i) acc2[i] = bv;
        __builtin_amdgcn_s_setprio(1);
#pragma unroll
        for (int ks = 0; ks < 8; ++ks) {
            f16x8 a = *(const f16x8*)&h_sm[(wave * 32 + l31) * LDH + ks * 16 + khalf * 8];
            acc2 = __builtin_amdgcn_mfma_f32_32x32x16_f16(a, A[ks], acc2, 0, 0, 0);
        }
        __builtin_amdgcn_s_setprio(0);
        // merged atomics: 32 lanes hit one full 128B line of out
#pragma unroll
        for (int r = 0; r < 16; ++r) {
            int row = m0 + wave * 32 + (r & 3) + 8 * (r >> 2) + 4 * khalf;
            atomicAdd(&out[(size_t)row * NO + l31], acc2[r]);
        }
    }
}

extern "C" void kernel_launch(void* const* d_in, const int* in_sizes, int n_in,
                              void* d_out, int out_size, void* d_ws, size_t ws_size,
                              hipStream_t stream) {
    const float* x  = (const float*)d_in[0];
    const float* W1 = (const float*)d_in[1];
    const float* b1 = (const float*)d_in[2];
    const float* Wh = (const float*)d_in[3];
    const float* bh = (const float*)d_in[4];
    const float* Wo = (const float*)d_in[5];
    const float* bo = (const float*)d_in[6];
    float* out = (float*)d_out;
    unsigned short* ws = (unsigned short*)d_ws;

    prep_weights4<<<432, 256, 0, stream>>>(Wh, Wo, x, ws, out);
    ngam_fused<<<NF * (BATCH / MT), 256, 0, stream>>>(W1, b1, bh, bo, ws, out);
}